// Round 11
// baseline (1080.602 us; speedup 1.0000x reference)
//
#include <hip/hip_runtime.h>

#define D     128
#define OD    384   // 3*D output row stride
#define NK    25    // KS^2 kernels
#define KCMAX 13    // k-chunk: G chunk 166MB bf16 stays L3-resident

typedef __attribute__((ext_vector_type(8))) short bf16x8;
typedef __attribute__((ext_vector_type(4))) float f32x4;
typedef const __attribute__((address_space(1))) void gv_t;
typedef __attribute__((address_space(3))) void lv_t;

__device__ inline unsigned short f2bf(float f) {
  unsigned int u = __float_as_uint(f);
  u += 0x7fffu + ((u >> 16) & 1u);
  return (unsigned short)(u >> 16);
}

// ---------------- preprocessing: counting sort of CORNERS by (dst, k) --------
// each edge contributes 4 corner-records {src, b(f32)} at k = w00+{0,1,5,6}.

__global__ __launch_bounds__(256) void count25_kernel(const int* __restrict__ dstA,
    const float* __restrict__ attr, int E, int* __restrict__ deg,
    int* __restrict__ cnt25) {
  int e = blockIdx.x * 256 + threadIdx.x;
  if (e >= E) return;
  int d = dstA[e];
  atomicAdd(&deg[d], 1);
  float v0 = attr[2 * e] * 4.0f;
  float v1 = attr[2 * e + 1] * 4.0f;
  int i0 = min(3, max(0, (int)v0));
  int i1 = min(3, max(0, (int)v1));
  int b = d * NK + i0 + 5 * i1;
  atomicAdd(&cnt25[b], 1);
  atomicAdd(&cnt25[b + 1], 1);
  atomicAdd(&cnt25[b + 5], 1);
  atomicAdd(&cnt25[b + 6], 1);
}

// ---------------- parallel exclusive scan over cnt[M] -> base[M+1] -----------

__global__ __launch_bounds__(1024) void scan_a_kernel(const int* __restrict__ cnt, int M,
    int* __restrict__ base, int* __restrict__ bsum) {
  __shared__ int tmp[1024];
  int tid = threadIdx.x;
  int e = blockIdx.x * 1024 + tid;
  int v = (e < M) ? cnt[e] : 0;
  tmp[tid] = v;
  __syncthreads();
#pragma unroll
  for (int off = 1; off < 1024; off <<= 1) {
    int t = (tid >= off) ? tmp[tid - off] : 0;
    __syncthreads();
    tmp[tid] += t;
    __syncthreads();
  }
  if (e <= M) base[e] = tmp[tid] - v;  // exclusive
  if (tid == 1023) bsum[blockIdx.x] = tmp[1023];
}

__global__ __launch_bounds__(256) void scan_b_kernel(int* __restrict__ bsum, int nblk) {
  __shared__ int tmp[256];
  __shared__ int carry;
  int tid = threadIdx.x;
  if (tid == 0) carry = 0;
  __syncthreads();
  for (int s = 0; s < nblk; s += 256) {
    int i = s + tid;
    int v = (i < nblk) ? bsum[i] : 0;
    tmp[tid] = v;
    __syncthreads();
#pragma unroll
    for (int off = 1; off < 256; off <<= 1) {
      int t = (tid >= off) ? tmp[tid - off] : 0;
      __syncthreads();
      tmp[tid] += t;
      __syncthreads();
    }
    if (i < nblk) bsum[i] = carry + tmp[tid] - v;
    __syncthreads();
    if (tid == 255) carry += tmp[255];
    __syncthreads();
  }
}

__global__ __launch_bounds__(256) void scan_c_kernel(int* __restrict__ base,
    int* __restrict__ cursor, const int* __restrict__ bsum, int M) {
  int e = blockIdx.x * 256 + threadIdx.x;
  if (e > M) return;
  int v = base[e] + bsum[e >> 10];
  base[e] = v;
  if (e < M) cursor[e] = v;
}

__global__ __launch_bounds__(256) void fill25_kernel(const int* __restrict__ srcA,
    const int* __restrict__ dstA, const float* __restrict__ attr, int E,
    int* __restrict__ cursor, uint2* __restrict__ recs) {
  int e = blockIdx.x * 256 + threadIdx.x;
  if (e >= E) return;
  int s = srcA[e], d = dstA[e];
  float v0 = attr[2 * e] * 4.0f;
  float v1 = attr[2 * e + 1] * 4.0f;
  int i0 = min(3, max(0, (int)v0));
  int i1 = min(3, max(0, (int)v1));
  float f0 = v0 - (float)i0;
  float f1 = v1 - (float)i1;
  int b = d * NK + i0 + 5 * i1;
  unsigned int su = (unsigned int)s;
  int p;
  p = atomicAdd(&cursor[b], 1);
  recs[p] = make_uint2(su, __float_as_uint((1.f - f0) * (1.f - f1)));
  p = atomicAdd(&cursor[b + 1], 1);
  recs[p] = make_uint2(su, __float_as_uint(f0 * (1.f - f1)));
  p = atomicAdd(&cursor[b + 5], 1);
  recs[p] = make_uint2(su, __float_as_uint((1.f - f0) * f1));
  p = atomicAdd(&cursor[b + 6], 1);
  recs[p] = make_uint2(su, __float_as_uint(f0 * f1));
}

// WT[n][kk] = bf16(W[kk/128][kk%128][n]); gridDim.y selects layer
__global__ __launch_bounds__(256) void wt_kernel(const float* __restrict__ W0,
    const float* __restrict__ W1, unsigned short* __restrict__ WT0,
    unsigned short* __restrict__ WT1) {
  int idx = blockIdx.x * 256 + threadIdx.x;  // over 128*3200
  if (idx >= 128 * NK * D) return;
  const float* W = blockIdx.y ? W1 : W0;
  unsigned short* WT = blockIdx.y ? WT1 : WT0;
  int n = idx / (NK * D);
  int kk = idx - n * (NK * D);
  WT[idx] = f2bf(W[(size_t)kk * D + n]);
}

// ---------------- gather: G[dst, kk, :] = sum_{corners(dst,k)} b * x[src] ----
// wave per dst; corners sorted by (dst,k) -> static-unrolled k-group loop with
// REGISTER accumulators (no LDS at all). 4-deep predicated batches per group.

__global__ __launch_bounds__(256) void gather_kernel(const int* __restrict__ base25,
    const uint2* __restrict__ recs, const unsigned short* __restrict__ Xb,
    unsigned short* __restrict__ Gc, int N, int KCc, int kc0) {
  int w = threadIdx.x >> 6, l = threadIdx.x & 63;
  int dst = blockIdx.x * 4 + w;
  if (dst >= N) return;
  const int l2 = l * 2;
  const int* bp = base25 + dst * NK + kc0;

  float2 accv[KCMAX];
#pragma unroll
  for (int kk = 0; kk < KCMAX; ++kk) {
    float2 a = make_float2(0.f, 0.f);
    if (kk < KCc) {
      int g0 = __builtin_amdgcn_readfirstlane(bp[kk]);
      int g1 = __builtin_amdgcn_readfirstlane(bp[kk + 1]);
      for (int j = g0; j < g1; j += 4) {
        uint2 r[4];
        unsigned int xp[4];
#pragma unroll
        for (int u = 0; u < 4; ++u) {
          int idx = (j + u < g1) ? (j + u) : (g1 - 1);
          r[u] = recs[idx];
        }
#pragma unroll
        for (int u = 0; u < 4; ++u)
          xp[u] = *(const unsigned int*)(Xb + (size_t)r[u].x * D + l2);
#pragma unroll
        for (int u = 0; u < 4; ++u) {
          float b = (j + u < g1) ? __uint_as_float(r[u].y) : 0.f;
          a.x = fmaf(b, __uint_as_float(xp[u] << 16), a.x);
          a.y = fmaf(b, __uint_as_float(xp[u] & 0xffff0000u), a.y);
        }
      }
    }
    accv[kk] = a;
  }

  unsigned short* gr = Gc + (size_t)dst * ((size_t)KCc * D);
#pragma unroll
  for (int kk = 0; kk < KCMAX; ++kk) {
    if (kk < KCc) {
      unsigned int pk =
          (unsigned int)f2bf(accv[kk].x) | ((unsigned int)f2bf(accv[kk].y) << 16);
      *(unsigned int*)(gr + kk * D + l2) = pk;
    }
  }
}

// ---------------- bf16 MFMA GEMM: Y[N,128] (+)= Gc[N,KCc*128] @ W[kchunk] ----
// 128x128 tile, 4 waves, BK=64, global_load_lds w/ pre-swizzled source (T2),
// 2-phase double-buffered pipeline.

__global__ __launch_bounds__(256) void gemm_kernel(
    const unsigned short* __restrict__ G, const unsigned short* __restrict__ WT,
    float* __restrict__ Y, int N, int KCc, int kc0, int first) {
  __shared__ __attribute__((aligned(16))) char At[2][16384];
  __shared__ __attribute__((aligned(16))) char Bt[2][16384];
  const int tid = threadIdx.x;
  const int w = tid >> 6;
  const int l = tid & 63;
  const int m0 = blockIdx.x * 128;
  const size_t ldG = (size_t)KCc * 256;  // bytes per G row
  const size_t ldW = (size_t)NK * 256;   // 6400 bytes per WT row

  const int lrow = l >> 3;                       // row within 8-row group
  const int scol = ((l & 7) * 16) ^ (lrow << 4); // swizzled source column byte

  f32x4 acc[2][8];
#pragma unroll
  for (int mr = 0; mr < 2; ++mr)
#pragma unroll
    for (int nc = 0; nc < 8; ++nc) {
      if (first) {
        acc[mr][nc] = (f32x4){0.f, 0.f, 0.f, 0.f};
      } else {
        int col = nc * 16 + (l & 15);
#pragma unroll
        for (int j = 0; j < 4; ++j) {
          int row = m0 + w * 32 + mr * 16 + (l >> 4) * 4 + j;
          acc[mr][nc][j] = (row < N) ? Y[(size_t)row * D + col] : 0.f;
        }
      }
    }

  const int steps = KCc * 2;
  auto STAGE = [&](int kt, int b) {
#pragma unroll
    for (int i = 0; i < 4; ++i) {  // A: 8 G-rows per load
      int row = w * 32 + i * 8 + lrow;
      int node = m0 + row;
      if (node > N - 1) node = N - 1;
      const char* src = (const char*)G + (size_t)node * ldG + kt * 128 + scol;
      __builtin_amdgcn_global_load_lds((gv_t*)src, (lv_t*)(At[b] + (w * 4 + i) * 1024),
                                       16, 0, 0);
    }
#pragma unroll
    for (int i = 0; i < 4; ++i) {  // B from WT (n-major)
      int nr = w * 32 + i * 8 + lrow;
      const char* src = (const char*)WT + (size_t)nr * ldW + kc0 * 256 + kt * 128 + scol;
      __builtin_amdgcn_global_load_lds((gv_t*)src, (lv_t*)(Bt[b] + (w * 4 + i) * 1024),
                                       16, 0, 0);
    }
  };

  STAGE(0, 0);
  __syncthreads();  // drains vmcnt(0): buf0 ready
  for (int kt = 0; kt < steps; ++kt) {
    const int cur = kt & 1;
    if (kt + 1 < steps) STAGE(kt + 1, cur ^ 1);  // issue next tile's loads now
#pragma unroll
    for (int ks = 0; ks < 2; ++ks) {
      int kb = ks * 64 + (l >> 4) * 16;
      bf16x8 a[2], b[8];
#pragma unroll
      for (int mr = 0; mr < 2; ++mr) {
        int r = w * 32 + mr * 16 + (l & 15);
        a[mr] = *(const bf16x8*)(At[cur] + r * 128 + (kb ^ ((r & 7) << 4)));
      }
#pragma unroll
      for (int nc = 0; nc < 8; ++nc) {
        int nr = nc * 16 + (l & 15);
        b[nc] = *(const bf16x8*)(Bt[cur] + nr * 128 + (kb ^ ((nr & 7) << 4)));
      }
#pragma unroll
      for (int mr = 0; mr < 2; ++mr)
#pragma unroll
        for (int nc = 0; nc < 8; ++nc)
          acc[mr][nc] =
              __builtin_amdgcn_mfma_f32_16x16x32_bf16(a[mr], b[nc], acc[mr][nc], 0, 0, 0);
    }
    __syncthreads();  // next buf ready, all reads of cur done
  }

#pragma unroll
  for (int mr = 0; mr < 2; ++mr)
#pragma unroll
    for (int nc = 0; nc < 8; ++nc) {
      int col = nc * 16 + (l & 15);
#pragma unroll
      for (int j = 0; j < 4; ++j) {
        int row = m0 + w * 32 + mr * 16 + (l >> 4) * 4 + j;
        if (row < N) Y[(size_t)row * D + col] = acc[mr][nc][j];
      }
    }
}

// ---------------- per-row l2norm / finalize ---------------------------------

__global__ __launch_bounds__(256) void l2norm_x_kernel(const float* __restrict__ x,
    float* __restrict__ out, unsigned short* __restrict__ xbf, int N) {
  int g = blockIdx.x * 256 + threadIdx.x;
  int n = g >> 6, lane = g & 63;
  if (n >= N) return;
  float2 v = *(const float2*)(x + (size_t)n * D + lane * 2);
  float ss = v.x * v.x + v.y * v.y;
#pragma unroll
  for (int m = 1; m < 64; m <<= 1) ss += __shfl_xor(ss, m, 64);
  float r = 1.0f / fmaxf(sqrtf(ss), 1e-12f);
  *(float2*)(out + (size_t)n * OD + lane * 2) = make_float2(v.x * r, v.y * r);
  unsigned int pk = (unsigned int)f2bf(v.x) | ((unsigned int)f2bf(v.y) << 16);
  *(unsigned int*)(xbf + (size_t)n * D + lane * 2) = pk;
}

__global__ __launch_bounds__(256) void finalize_kernel(const float* __restrict__ y,
    const int* __restrict__ deg, const float* __restrict__ bias, float* __restrict__ out,
    unsigned short* __restrict__ xnext, int N) {
  int g = blockIdx.x * 256 + threadIdx.x;
  int n = g >> 6, lane = g & 63;
  if (n >= N) return;
  float inv = 1.0f / (float)max(deg[n], 1);
  float2 a = *(const float2*)(y + (size_t)n * D + lane * 2);
  float2 b = *(const float2*)(bias + lane * 2);
  float h0 = a.x * inv + b.x;
  float h1 = a.y * inv + b.y;
  float ss = h0 * h0 + h1 * h1;
#pragma unroll
  for (int m = 1; m < 64; m <<= 1) ss += __shfl_xor(ss, m, 64);
  float r = 1.0f / fmaxf(sqrtf(ss), 1e-12f);
  *(float2*)(out + (size_t)n * OD + lane * 2) = make_float2(h0 * r, h1 * r);
  if (xnext) {
    unsigned int pk = (unsigned int)f2bf(fmaxf(h0, 0.f)) |
                      ((unsigned int)f2bf(fmaxf(h1, 0.f)) << 16);
    *(unsigned int*)(xnext + (size_t)n * D + lane * 2) = pk;
  }
}

// ---------------- launch -----------------------------------------------------

extern "C" void kernel_launch(void* const* d_in, const int* in_sizes, int n_in,
                              void* d_out, int out_size, void* d_ws, size_t ws_size,
                              hipStream_t stream) {
  const float* x    = (const float*)d_in[0];
  const int*   ei   = (const int*)d_in[1];
  const float* attr = (const float*)d_in[2];
  const float* w0   = (const float*)d_in[3];
  const float* b0   = (const float*)d_in[4];
  const float* w1   = (const float*)d_in[5];
  const float* b1   = (const float*)d_in[6];
  float* out = (float*)d_out;

  const int N = in_sizes[0] / D;
  const int E = in_sizes[1] / 2;
  const int* srcA = ei;
  const int* dstA = ei + E;
  const int M25 = N * NK;

  char* p = (char*)d_ws;
  auto carve = [&](size_t bytes) -> char* {
    char* r = p;
    p += (bytes + 255) & ~(size_t)255;
    return r;
  };
  unsigned short* xbf    = (unsigned short*)carve((size_t)N * D * 2);
  unsigned short* xtmp   = (unsigned short*)carve((size_t)N * D * 2);
  float*          ygemm  = (float*)carve((size_t)N * D * 4);
  int*            deg    = (int*)carve((size_t)N * 4);
  int*            cnt25  = (int*)carve((size_t)M25 * 4);
  int*            base25 = (int*)carve(((size_t)M25 + 1) * 4);
  int*            cursor = (int*)carve((size_t)M25 * 4);
  int*            bsum   = (int*)carve(8192);
  uint2*          recs   = (uint2*)carve((size_t)E * 4 * 8);
  unsigned short* WT0    = (unsigned short*)carve((size_t)128 * NK * D * 2);
  unsigned short* WT1    = (unsigned short*)carve((size_t)128 * NK * D * 2);
  size_t used = (size_t)(p - (char*)d_ws);
  size_t remain = (ws_size > used) ? (ws_size - used) : 0;
  int KCg = (int)(remain / ((size_t)N * D * 2));  // bf16 G bytes per k
  if (KCg > KCMAX) KCg = KCMAX;
  if (KCg < 1) KCg = 1;
  unsigned short* Gc = (unsigned short*)carve((size_t)N * (size_t)KCg * D * 2);
  (void)n_in; (void)out_size;

  hipMemsetAsync(deg, 0, (size_t)N * 4, stream);
  hipMemsetAsync(cnt25, 0, (size_t)M25 * 4, stream);

  int eb = (E + 255) / 256;
  count25_kernel<<<eb, 256, 0, stream>>>(dstA, attr, E, deg, cnt25);
  int nblk_a = (M25 + 1 + 1023) / 1024;
  scan_a_kernel<<<nblk_a, 1024, 0, stream>>>(cnt25, M25, base25, bsum);
  scan_b_kernel<<<1, 256, 0, stream>>>(bsum, nblk_a);
  scan_c_kernel<<<(M25 + 1 + 255) / 256, 256, 0, stream>>>(base25, cursor, bsum, M25);
  fill25_kernel<<<eb, 256, 0, stream>>>(srcA, dstA, attr, E, cursor, recs);
  int wtb = (128 * NK * D + 255) / 256;
  wt_kernel<<<dim3(wtb, 2), 256, 0, stream>>>(w0, w1, WT0, WT1);

  int nb = (N * 64 + 255) / 256;
  l2norm_x_kernel<<<nb, 256, 0, stream>>>(x, out, xbf, N);

  int gbg = (N + 3) / 4;              // gather: 4 waves/block, wave per dst
  int gbm = (N + 127) / 128;          // gemm: 128-row tiles
  const unsigned short* xin = xbf;
  const float* Bv[2] = {b0, b1};
  const unsigned short* WTl[2] = {WT0, WT1};
  for (int layer = 0; layer < 2; ++layer) {
    int first = 1;
    for (int kc0 = 0; kc0 < NK; kc0 += KCg) {
      int KCc = min(KCg, NK - kc0);
      gather_kernel<<<gbg, 256, 0, stream>>>(base25, recs, xin, Gc, N, KCc, kc0);
      gemm_kernel<<<gbm, 256, 0, stream>>>(Gc, WTl[layer], ygemm, N, KCc, kc0, first);
      first = 0;
    }
    finalize_kernel<<<nb, 256, 0, stream>>>(ygemm, deg, Bv[layer], out + D * (layer + 1),
                                            layer == 0 ? xtmp : nullptr, N);
    xin = xtmp;
  }
}